// Round 4
// baseline (265.387 us; speedup 1.0000x reference)
//
#include <hip/hip_runtime.h>
#include <math.h>

// Shapes (fixed): B=32, M=2, C=256, H=W=16, N=256, DIM=256, THR=0.1, RATIO=0.8
// out: fused (32,256,16,16) = 2,097,152 floats, then auto_enc_loss (1 float)
//
// R4: convs as bf16 implicit GEMM, 64px x 64oc tiles, BK=64, double-buffered
// LDS (2x16KB) with raw s_barrier + own vmcnt (prefetch flies across barrier).
// 1024 blocks = 4 blocks/CU on the 64-img convs (m114 implicit overlap).

typedef __attribute__((ext_vector_type(8))) short short8;
typedef __attribute__((ext_vector_type(4))) float f32x4;

__device__ __forceinline__ void gload_lds16(const void* g, void* l) {
  __builtin_amdgcn_global_load_lds(
      (const __attribute__((address_space(1))) void*)g,
      (__attribute__((address_space(3))) void*)l, 16, 0, 0);
}

__device__ __forceinline__ unsigned short f2bf(float f) {
  unsigned u = __float_as_uint(f);
  unsigned r = (u + 0x7FFFu + ((u >> 16) & 1u)) >> 16;  // RNE
  return (unsigned short)r;
}

__device__ __forceinline__ unsigned mapf(float f) {
  unsigned u = __float_as_uint(f);
  return (u & 0x80000000u) ? ~u : (u | 0x80000000u);   // monotone float->uint
}
__device__ __forceinline__ float unmapf(unsigned u) {
  unsigned v = (u & 0x80000000u) ? (u & 0x7fffffffu) : ~u;
  return __uint_as_float(v);
}

// ---------------- merged prep: pack | weight-repack | halo-zero | slots | init
__global__ __launch_bounds__(256) void prep_k(
    const float* __restrict__ cf, const float* __restrict__ we,
    const float* __restrict__ wd, const float* __restrict__ fv,
    unsigned short* __restrict__ Xp, unsigned short* __restrict__ WrE,
    unsigned short* __restrict__ WrD, int* __restrict__ smr,
    float* __restrict__ vd, float4* __restrict__ sraw4,
    float* __restrict__ lacc, unsigned* __restrict__ mm) {
  const int bx = blockIdx.x, t = threadIdx.x;
  if (bx < 2048) {                       // pack: cf NCHW f32 -> padded NHWC bf16
    int idx = bx * 256 + t;
    int ch = idx & 31, p = (idx >> 5) & 255, img = idx >> 13;
    int ic0 = ch * 8;
    const float* sp = cf + (size_t)img * 65536 + (size_t)ic0 * 256 + p;
    unsigned short h[8];
#pragma unroll
    for (int i = 0; i < 8; ++i) h[i] = f2bf(sp[i * 256]);
    int y = p >> 4, x = p & 15;
    uint4 u;
    u.x = h[0] | (h[1] << 16); u.y = h[2] | (h[3] << 16);
    u.z = h[4] | (h[5] << 16); u.w = h[6] | (h[7] << 16);
    *(uint4*)&Xp[(size_t)img * 82944 + (size_t)(y * 18 + x + 19) * 256 + ic0] = u;
  } else if (bx < 2624) {                // wrk: OIHW f32 -> Wr[oc][s][ic] bf16
    int idx = (bx - 2048) * 256 + t;
    int ch = idx & 31, rest = idx >> 5;
    int s = rest % 9, ocx = rest / 9;
    int oc = ocx & 255, cv = ocx >> 8;
    const float* w = cv ? wd : we;
    unsigned short* o = cv ? WrD : WrE;
    int ic0 = ch * 8;
    unsigned short h[8];
#pragma unroll
    for (int i = 0; i < 8; ++i) h[i] = f2bf(w[(size_t)oc * 2304 + (ic0 + i) * 9 + s]);
    uint4 u;
    u.x = h[0] | (h[1] << 16); u.y = h[2] | (h[3] << 16);
    u.z = h[4] | (h[5] << 16); u.w = h[6] | (h[7] << 16);
    *(uint4*)&o[(size_t)oc * 2304 + s * 256 + ic0] = u;
  } else if (bx < 2752) {                // halo zero: Xp imgs 0..63, Midp 64..127
    int img = bx - 2624;
    uint4* base = (uint4*)Xp + (size_t)img * 10368;
    uint4 z; z.x = z.y = z.z = z.w = 0;
    for (int it = t; it < 2176; it += 256) {
      int px = it >> 5, c = it & 31;
      int y, x;
      if (px < 18)      { y = 0;  x = px; }
      else if (px < 36) { y = 17; x = px - 18; }
      else if (px < 52) { y = px - 35; x = 0; }
      else              { y = px - 51; x = 17; }
      base[(y * 18 + x) * 32 + c] = z;
    }
  } else if (bx < 2784) {                // slots: rank budget + dest maps
    const int b = bx - 2752;
    const float v0 = fv[(size_t)b * 512 + t];
    const float v1 = fv[(size_t)b * 512 + 256 + t];
    const unsigned long long bal0 = __ballot(v0 > 0.1f);
    const unsigned long long bal1 = __ballot(v1 > 0.1f);
    __shared__ int cnt0[4], cnt1[4], fc[2];
    const int wid = t >> 6, lane = t & 63;
    if (lane == 0) { cnt0[wid] = __popcll(bal0); cnt1[wid] = __popcll(bal1); }
    smr[b * 256 + t] = -1;
    vd[b * 256 + t] = 0.f;
    __syncthreads();
    if (t == 0) {
      int c0 = cnt0[0] + cnt0[1] + cnt0[2] + cnt0[3];
      int c1 = cnt1[0] + cnt1[1] + cnt1[2] + cnt1[3];
      int total = c0 + c1;
      int f0, f1;
      if (total > 256) {
        int a0 = (int)rintf(256.0f * (float)c0 / (float)total);
        f0 = a0; f1 = 256 - a0;
      } else { f0 = c0; f1 = c1; }
      fc[0] = max(f0, 0); fc[1] = max(f1, 0);
    }
    __syncthreads();
    const int c0 = fc[0], c1 = fc[1];
    if (t < c0) { smr[b * 256 + t] = t; vd[b * 256 + t] = v0; }
    if (t < c1) {
      int d = c0 + t;
      if (d < 256) { smr[b * 256 + d] = 256 + t; vd[b * 256 + d] = v1; }
    }
  } else {                               // zero sraw (24 blocks) + init (1)
    int z = bx - 2784;
    if (z < 24) {
      float4 zz; zz.x = zz.y = zz.z = zz.w = 0.f;
      sraw4[z * 256 + t] = zz;
    } else if (t == 0) {
      lacc[0] = 0.f; mm[0] = 0xFFFFFFFFu; mm[1] = 0u;
    }
  }
}

// ---------------- MFMA conv: out[p][oc] = sum_k X[p][k]W[oc][k]
// Tile 64px x 64oc, BK=64, 36 kits, dbuf LDS. grid (16, nimg): bx = pt*4+ot.
// EPI: 0=enc(relu->NHWC bf16), 1=dec+loss, 2=dec(rec)->NCHW f32 + minmax
template<int EPI>
__global__ __launch_bounds__(256, 4) void convmma_k(
    const unsigned short* __restrict__ Xin, const unsigned short* __restrict__ Wr,
    const float* __restrict__ bias, const float* __restrict__ cfref,
    unsigned short* __restrict__ outp, float* __restrict__ outf,
    float* __restrict__ lacc, unsigned* __restrict__ mm) {
  __shared__ __align__(16) unsigned short S[2][8192];  // [buf][A 8KB | B 8KB]
  const int t = threadIdx.x, lane = t & 63, wave = t >> 6;
  const int img = blockIdx.y, pt = blockIdx.x >> 2, ot = blockIdx.x & 3;

  int laneA[2], laneB[2];
#pragma unroll
  for (int j = 0; j < 2; ++j) {
    int id = (wave * 2 + j) * 64 + lane;
    int row = id >> 3, q = (id & 7) ^ (row & 7);
    int p = pt * 64 + row, y = p >> 4, x = p & 15;
    laneA[j] = (y * 18 + x) * 512 + q * 16;
    laneB[j] = (ot * 64 + row) * 4608 + q * 16;
  }
  const char* Ag = (const char*)Xin + (size_t)img * 165888;
  const char* Bg = (const char*)Wr;

  const int mlane = lane & 15, quad = lane >> 4;
  const int mw = wave >> 1, nw = wave & 1;
  int aoff[2][2], boff[2][2];
#pragma unroll
  for (int ks = 0; ks < 2; ++ks) {
#pragma unroll
    for (int i = 0; i < 2; ++i) {
      int rowm = mw * 32 + i * 16 + mlane;
      aoff[i][ks] = rowm * 128 + (((ks * 4 + quad) ^ (rowm & 7)) * 16);
      int rown = nw * 32 + i * 16 + mlane;
      boff[i][ks] = 8192 + rown * 128 + (((ks * 4 + quad) ^ (rown & 7)) * 16);
    }
  }

  auto stage = [&](int kit, int buf) {
    int s = kit >> 2;
    int dy = s / 3, dx = s - dy * 3;
    int aG = (dy * 18 + dx) * 512 + (kit & 3) * 128;
    int bG = kit * 128;
    char* dst = (char*)S[buf];
#pragma unroll
    for (int j = 0; j < 2; ++j)
      gload_lds16(Ag + laneA[j] + aG, dst + (wave * 2 + j) * 1024);
#pragma unroll
    for (int j = 0; j < 2; ++j)
      gload_lds16(Bg + laneB[j] + bG, dst + 8192 + (wave * 2 + j) * 1024);
  };

  f32x4 acc[2][2] = {};
  stage(0, 0);
  for (int kit = 0; kit < 36; ++kit) {
    int cur = kit & 1;
    asm volatile("s_waitcnt vmcnt(0)" ::: "memory");
    asm volatile("s_barrier" ::: "memory");
    if (kit + 1 < 36) stage(kit + 1, 1 - cur);  // prefetch flies over compute
    const char* Sb = (const char*)S[cur];
#pragma unroll
    for (int ks = 0; ks < 2; ++ks) {
      short8 af[2], bf[2];
#pragma unroll
      for (int i = 0; i < 2; ++i) {
        af[i] = *(const short8*)(Sb + aoff[i][ks]);
        bf[i] = *(const short8*)(Sb + boff[i][ks]);
      }
#pragma unroll
      for (int i = 0; i < 2; ++i)
#pragma unroll
        for (int n = 0; n < 2; ++n)
          acc[i][n] = __builtin_amdgcn_mfma_f32_16x16x32_bf16(af[i], bf[n], acc[i][n], 0, 0, 0);
    }
  }

  if (EPI == 0) {
#pragma unroll
    for (int i = 0; i < 2; ++i) {
      int m0 = pt * 64 + mw * 32 + i * 16 + quad * 4;
#pragma unroll
      for (int n = 0; n < 2; ++n) {
        int oc = ot * 64 + nw * 32 + n * 16 + mlane;
        float bv = bias[oc];
#pragma unroll
        for (int r = 0; r < 4; ++r) {
          int p = m0 + r;
          int y = p >> 4, x = p & 15;
          float v = fmaxf(acc[i][n][r] + bv, 0.f);
          outp[(size_t)img * 82944 + (size_t)(y * 18 + x + 19) * 256 + oc] = f2bf(v);
        }
      }
    }
  } else if (EPI == 1) {
    float ls = 0.f;
#pragma unroll
    for (int i = 0; i < 2; ++i) {
      int m0 = pt * 64 + mw * 32 + i * 16 + quad * 4;
#pragma unroll
      for (int n = 0; n < 2; ++n) {
        int oc = ot * 64 + nw * 32 + n * 16 + mlane;
        float bv = bias[oc];
        float4 c4 = *(const float4*)(cfref + (size_t)img * 65536 + (size_t)oc * 256 + m0);
        float d0 = acc[i][n][0] + bv - c4.x;
        float d1 = acc[i][n][1] + bv - c4.y;
        float d2 = acc[i][n][2] + bv - c4.z;
        float d3 = acc[i][n][3] + bv - c4.w;
        ls += d0 * d0 + d1 * d1 + d2 * d2 + d3 * d3;
      }
    }
#pragma unroll
    for (int off = 32; off; off >>= 1) ls += __shfl_down(ls, off);
    __shared__ float sred[4];
    if (lane == 0) sred[wave] = ls;
    __syncthreads();
    if (t == 0) atomicAdd(lacc, sred[0] + sred[1] + sred[2] + sred[3]);
  } else {
    float mn = INFINITY, mx = -INFINITY;
#pragma unroll
    for (int i = 0; i < 2; ++i) {
      int m0 = pt * 64 + mw * 32 + i * 16 + quad * 4;
#pragma unroll
      for (int n = 0; n < 2; ++n) {
        int oc = ot * 64 + nw * 32 + n * 16 + mlane;
        float bv = bias[oc];
        float4 v;
        v.x = acc[i][n][0] + bv; v.y = acc[i][n][1] + bv;
        v.z = acc[i][n][2] + bv; v.w = acc[i][n][3] + bv;
        mn = fminf(mn, fminf(fminf(v.x, v.y), fminf(v.z, v.w)));
        mx = fmaxf(mx, fmaxf(fmaxf(v.x, v.y), fmaxf(v.z, v.w)));
        *(float4*)(outf + (size_t)img * 65536 + (size_t)oc * 256 + m0) = v;
      }
    }
#pragma unroll
    for (int off = 32; off; off >>= 1) {
      mn = fminf(mn, __shfl_down(mn, off));
      mx = fmaxf(mx, __shfl_down(mx, off));
    }
    __shared__ float smn[4], smx[4];
    if (lane == 0) { smn[wave] = mn; smx[wave] = mx; }
    __syncthreads();
    if (t == 0) {
      mn = fminf(fminf(smn[0], smn[1]), fminf(smn[2], smn[3]));
      mx = fmaxf(fmaxf(smx[0], smx[1]), fmaxf(smx[2], smx[3]));
      atomicMin(&mm[0], mapf(mn));
      atomicMax(&mm[1], mapf(mx));
    }
  }
}

// ---------------- merged: ansb [0,1024) | bmt-transpose [1024,1152) | Recp halo [1152,1184)
__global__ __launch_bounds__(256) void ansbmt_k(
    const float* __restrict__ fs, const float* __restrict__ fd,
    const int* __restrict__ smr, const float* __restrict__ vd,
    unsigned short* __restrict__ Ans, unsigned short* __restrict__ BmT,
    unsigned short* __restrict__ Recp) {
  const int bx = blockIdx.x, t = threadIdx.x;
  if (bx < 1024) {                       // Ans[b][c][j] = ns[c][j]*v_j
    int idx = bx * 256 + t;
    int ch = idx & 31, c = (idx >> 5) & 255, b = idx >> 13;
    int j0 = ch * 8;
    int si = smr[b * 256 + c];
    unsigned short h[8] = {0, 0, 0, 0, 0, 0, 0, 0};
    if (si >= 0) {
      int m = si >> 8, r = si & 255;
      const float* fp = fs + (((size_t)b * 2 + m) * 256 + r) * 256 + j0;
      const float* vp = vd + b * 256 + j0;
#pragma unroll
      for (int i = 0; i < 8; ++i) h[i] = f2bf(fp[i] * vp[i]);
    }
    uint4 u;
    u.x = h[0] | (h[1] << 16); u.y = h[2] | (h[3] << 16);
    u.z = h[4] | (h[5] << 16); u.w = h[6] | (h[7] << 16);
    *(uint4*)&Ans[(size_t)b * 65536 + c * 256 + j0] = u;
  } else if (bx < 1152) {                // BmT[b][p][j] = fd[b,m_p,j,r_p]
    __shared__ float sIn[4096];          // 8 j x 2 m x 256 r
    const int b = (bx - 1024) >> 2, bz = (bx - 1024) & 3;
    const int sp = smr[b * 256 + t];
    const int m_p = sp >> 8, r_p = sp & 255;
    for (int jg = bz * 8; jg < bz * 8 + 8; ++jg) {
      __syncthreads();
#pragma unroll
      for (int u = 0; u < 4; ++u) {
        int q = t * 4 + u;
        int rr = q >> 6, w = q & 63;
        int m = rr >> 3, i = rr & 7;
        float4 f = ((const float4*)fd)[((size_t)(b * 2 + m) * 256 + jg * 8 + i) * 64 + w];
        *(float4*)&sIn[i * 512 + m * 256 + w * 4] = f;
      }
      __syncthreads();
      unsigned short h[8] = {0, 0, 0, 0, 0, 0, 0, 0};
      if (sp >= 0) {
#pragma unroll
        for (int i = 0; i < 8; ++i) h[i] = f2bf(sIn[i * 512 + m_p * 256 + r_p]);
      }
      uint4 u;
      u.x = h[0] | (h[1] << 16); u.y = h[2] | (h[3] << 16);
      u.z = h[4] | (h[5] << 16); u.w = h[6] | (h[7] << 16);
      *(uint4*)&BmT[(size_t)b * 65536 + t * 256 + jg * 8] = u;
    }
  } else {                               // Recp halo zero (32 imgs)
    int img = bx - 1152;
    uint4* base = (uint4*)Recp + (size_t)img * 10368;
    uint4 z; z.x = z.y = z.z = z.w = 0;
    for (int it = t; it < 2176; it += 256) {
      int px = it >> 5, c = it & 31;
      int y, x;
      if (px < 18)      { y = 0;  x = px; }
      else if (px < 36) { y = 17; x = px - 18; }
      else if (px < 52) { y = px - 35; x = 0; }
      else              { y = px - 51; x = 17; }
      base[(y * 18 + x) * 32 + c] = z;
    }
  }
}

// rec^T[p][c] = sum_j BmT[p][j]*Ans[c][j] -> Recp padded NHWC bf16
// Tile 64p x 64c, BK=64, 4 kits, dbuf. grid (16, 32): bx = pt*4 + ct.
__global__ __launch_bounds__(256, 4) void recgemm_k(const unsigned short* __restrict__ BmT,
                                                    const unsigned short* __restrict__ Ans,
                                                    unsigned short* __restrict__ Recp) {
  __shared__ __align__(16) unsigned short S[2][8192];
  const int t = threadIdx.x, lane = t & 63, wave = t >> 6;
  const int b = blockIdx.y, pt = blockIdx.x >> 2, ct = blockIdx.x & 3;

  int laneA[2], laneB[2];
#pragma unroll
  for (int j = 0; j < 2; ++j) {
    int id = (wave * 2 + j) * 64 + lane;
    int row = id >> 3, q = (id & 7) ^ (row & 7);
    laneA[j] = (pt * 64 + row) * 512 + q * 16;
    laneB[j] = (ct * 64 + row) * 512 + q * 16;
  }
  const char* Ag = (const char*)BmT + (size_t)b * 131072;
  const char* Bg = (const char*)Ans + (size_t)b * 131072;

  const int mlane = lane & 15, quad = lane >> 4;
  const int mw = wave >> 1, nw = wave & 1;
  int aoff[2][2], boff[2][2];
#pragma unroll
  for (int ks = 0; ks < 2; ++ks) {
#pragma unroll
    for (int i = 0; i < 2; ++i) {
      int rowm = mw * 32 + i * 16 + mlane;
      aoff[i][ks] = rowm * 128 + (((ks * 4 + quad) ^ (rowm & 7)) * 16);
      int rown = nw * 32 + i * 16 + mlane;
      boff[i][ks] = 8192 + rown * 128 + (((ks * 4 + quad) ^ (rown & 7)) * 16);
    }
  }

  auto stage = [&](int kit, int buf) {
    int g = kit * 128;
    char* dst = (char*)S[buf];
#pragma unroll
    for (int j = 0; j < 2; ++j)
      gload_lds16(Ag + laneA[j] + g, dst + (wave * 2 + j) * 1024);
#pragma unroll
    for (int j = 0; j < 2; ++j)
      gload_lds16(Bg + laneB[j] + g, dst + 8192 + (wave * 2 + j) * 1024);
  };

  f32x4 acc[2][2] = {};
  stage(0, 0);
  for (int kit = 0; kit < 4; ++kit) {
    int cur = kit & 1;
    asm volatile("s_waitcnt vmcnt(0)" ::: "memory");
    asm volatile("s_barrier" ::: "memory");
    if (kit + 1 < 4) stage(kit + 1, 1 - cur);
    const char* Sb = (const char*)S[cur];
#pragma unroll
    for (int ks = 0; ks < 2; ++ks) {
      short8 af[2], bf[2];
#pragma unroll
      for (int i = 0; i < 2; ++i) {
        af[i] = *(const short8*)(Sb + aoff[i][ks]);
        bf[i] = *(const short8*)(Sb + boff[i][ks]);
      }
#pragma unroll
      for (int i = 0; i < 2; ++i)
#pragma unroll
        for (int n = 0; n < 2; ++n)
          acc[i][n] = __builtin_amdgcn_mfma_f32_16x16x32_bf16(af[i], bf[n], acc[i][n], 0, 0, 0);
    }
  }

#pragma unroll
  for (int i = 0; i < 2; ++i) {
    int m0 = pt * 64 + mw * 32 + i * 16 + quad * 4;
#pragma unroll
    for (int n = 0; n < 2; ++n) {
      int cc = ct * 64 + nw * 32 + n * 16 + mlane;
#pragma unroll
      for (int r = 0; r < 4; ++r) {
        int p = m0 + r;
        int y = p >> 4, x = p & 15;
        Recp[(size_t)b * 82944 + (size_t)(y * 18 + x + 19) * 256 + cc] = f2bf(acc[i][n][r]);
      }
    }
  }
}

// 256->1 score conv partials, ic-split 8-way, atomicAdd into sraw (pre-zeroed)
__global__ __launch_bounds__(256) void score_conv_k(
    const float* __restrict__ rec2, const float* __restrict__ cf,
    const float* __restrict__ wval, const unsigned* __restrict__ mm,
    float* __restrict__ sraw) {
  const int b = blockIdx.x, phase = blockIdx.y, icc = blockIdx.z;
  const int t = threadIdx.x;
  const int row = t >> 4, col = t & 15;
  __shared__ float s_in[8 * 360];
  __shared__ float s_wv[72];
  for (int i = t; i < 8 * 360; i += 256) s_in[i] = 0.f;
  const float* src;
  float sc = 1.f, sh = 0.f;
  int wofs;
  if (phase == 0) {
    src = rec2 + (size_t)b * 65536;
    float mn = unmapf(mm[0]), mx = unmapf(mm[1]);
    sc = 2.f / (mx - mn);
    sh = -mn * sc - 1.f;
    wofs = 0;
  } else {
    src = cf + ((size_t)b * 2 + (phase - 1)) * 65536;
    wofs = 2304;
  }
  float acc = 0.f;
  for (int ic0 = icc * 32; ic0 < icc * 32 + 32; ic0 += 8) {
    __syncthreads();
#pragma unroll
    for (int i = 0; i < 8; ++i) {
      float v = src[(ic0 + i) * 256 + t];
      if (phase == 0) v = fmaf(v, sc, sh);
      s_in[i * 360 + (row + 1) * 20 + (col + 1)] = v;
    }
    if (t < 72) s_wv[t] = wval[wofs + ic0 * 9 + t];
    __syncthreads();
#pragma unroll
    for (int i = 0; i < 8; ++i)
#pragma unroll
      for (int ky = 0; ky < 3; ++ky)
#pragma unroll
        for (int kx = 0; kx < 3; ++kx)
          acc += s_in[i * 360 + (row + ky) * 20 + (col + kx)] * s_wv[i * 9 + ky * 3 + kx];
  }
  atomicAdd(&sraw[((size_t)b * 3 + phase) * 256 + t], acc);
}

__global__ void fuse_k(const float* __restrict__ cf, const float* __restrict__ rec2,
                       const float* __restrict__ sraw, const float* __restrict__ bval,
                       const unsigned* __restrict__ mm, const float* __restrict__ lacc,
                       float* __restrict__ outp) {
  const int idx = blockIdx.x * 256 + threadIdx.x;
  const int b = idx >> 16;
  const int rest = idx & 65535;
  const int pos = idx & 255;
  const float mn = unmapf(mm[0]), mx = unmapf(mm[1]);
  const float sc = 2.f / (mx - mn), sh = -mn * sc - 1.f;
  const float srec = sraw[(size_t)b * 768 + pos];
  const float sc0 = sraw[(size_t)b * 768 + 256 + pos];
  const float sc1 = sraw[(size_t)b * 768 + 512 + pos];
  const float bv = bval[0];
  const float z0 = fmaxf(srec + sc0 + bv, 0.f);
  const float z1 = fmaxf(srec + sc1 + bv, 0.f);
  const float s0 = 1.f / (1.f + expf(-z0));
  const float s1 = 1.f / (1.f + expf(-z1));
  const float w0 = 1.f / (1.f + expf(s1 - s0));  // softmax over 2 modalities
  const float w1 = 1.f - w0;
  const float rn = fmaf(rec2[idx], sc, sh);
  const float f0 = cf[(size_t)b * 131072 + rest];
  const float f1 = cf[(size_t)b * 131072 + 65536 + rest];
  outp[idx] = 0.2f * (w0 * f0 + w1 * f1) + 0.8f * rn;
  if (idx == 0) outp[2097152] = lacc[0] * (1.f / 4194304.f);
}

extern "C" void kernel_launch(void* const* d_in, const int* in_sizes, int n_in,
                              void* d_out, int out_size, void* d_ws, size_t ws_size,
                              hipStream_t stream) {
  const float* cf    = (const float*)d_in[0];
  const float* fs    = (const float*)d_in[1];
  const float* fv    = (const float*)d_in[2];
  const float* fd    = (const float*)d_in[3];
  const float* w_enc = (const float*)d_in[4];
  const float* b_enc = (const float*)d_in[5];
  const float* w_dec = (const float*)d_in[6];
  const float* b_dec = (const float*)d_in[7];
  const float* w_val = (const float*)d_in[8];
  const float* b_val = (const float*)d_in[9];
  float* out = (float*)d_out;
  float* wsf = (float*)d_ws;

  // ws layout (float offsets):
  //   Xp 64-img padded NHWC bf16 [0, 2654208) -- dead after enc conv
  //     Ans @0, BmT @1048576 (written after enc conv)
  //   Midp 64-img [2654208, 5308416) -- dead after loss conv
  //     Recp 32-img @2654208 (halo re-zeroed in ansbmt_k)
  unsigned short* Xp   = (unsigned short*)wsf;
  unsigned short* Ans  = (unsigned short*)wsf;
  unsigned short* BmT  = (unsigned short*)(wsf + 1048576);
  unsigned short* Midp = (unsigned short*)(wsf + 2654208);
  unsigned short* Recp = (unsigned short*)(wsf + 2654208);
  float* rec2 = wsf + 5308416;                    // 2,097,152 (NCHW f32)
  unsigned short* WrE = (unsigned short*)(wsf + 7405568);
  unsigned short* WrD = (unsigned short*)(wsf + 7700480);
  float* sraw = wsf + 7995392;                    // 24,576
  float* vd   = wsf + 8019968;                    // 8,192
  int*   smr  = (int*)(wsf + 8028160);            // 8,192
  float* lacc = wsf + 8036352;
  unsigned* mm = (unsigned*)(wsf + 8036354);

  prep_k<<<2809, 256, 0, stream>>>(cf, w_enc, w_dec, fv, Xp, WrE, WrD, smr, vd,
                                   (float4*)sraw, lacc, mm);
  convmma_k<0><<<dim3(16, 64), 256, 0, stream>>>(Xp, WrE, b_enc, nullptr, Midp, nullptr, nullptr, nullptr);
  convmma_k<1><<<dim3(16, 64), 256, 0, stream>>>(Midp, WrD, b_dec, cf, nullptr, nullptr, lacc, nullptr);
  ansbmt_k<<<1184, 256, 0, stream>>>(fs, fd, smr, vd, Ans, BmT, Recp);
  recgemm_k<<<dim3(16, 32), 256, 0, stream>>>(BmT, Ans, Recp);
  convmma_k<2><<<dim3(16, 32), 256, 0, stream>>>(Recp, WrD, b_dec, nullptr, nullptr, rec2, nullptr, mm);
  score_conv_k<<<dim3(32, 3, 8), 256, 0, stream>>>(rec2, cf, w_val, mm, sraw);
  fuse_k<<<8192, 256, 0, stream>>>(cf, rec2, sraw, b_val, mm, lacc, out);
}

// Round 6
// 242.896 us; speedup vs baseline: 1.0926x; 1.0926x over previous
//
#include <hip/hip_runtime.h>
#include <math.h>

// Shapes (fixed): B=32, M=2, C=256, H=W=16, N=256, DIM=256, THR=0.1, RATIO=0.8
// out: fused (32,256,16,16) = 2,097,152 floats, then auto_enc_loss (1 float)
//
// R6 = R5 with the B-tile LDS read-base fixed (8192, matching staging; R5 read
// at 16384 -> OOB garbage -> NaN). Convs: bf16 implicit GEMM, 64px x 128oc,
// BK=64, 3-deep LDS pipeline (vmcnt(6): prefetch stays in flight across
// barriers), XCD-pinned image mapping.

typedef __attribute__((ext_vector_type(8))) short short8;
typedef __attribute__((ext_vector_type(4))) float f32x4;

__device__ __forceinline__ void gload_lds16(const void* g, void* l) {
  __builtin_amdgcn_global_load_lds(
      (const __attribute__((address_space(1))) void*)g,
      (__attribute__((address_space(3))) void*)l, 16, 0, 0);
}

__device__ __forceinline__ unsigned short f2bf(float f) {
  unsigned u = __float_as_uint(f);
  unsigned r = (u + 0x7FFFu + ((u >> 16) & 1u)) >> 16;  // RNE
  return (unsigned short)r;
}

__device__ __forceinline__ unsigned mapf(float f) {
  unsigned u = __float_as_uint(f);
  return (u & 0x80000000u) ? ~u : (u | 0x80000000u);   // monotone float->uint
}
__device__ __forceinline__ float unmapf(unsigned u) {
  unsigned v = (u & 0x80000000u) ? (u & 0x7fffffffu) : ~u;
  return __uint_as_float(v);
}

// ---------------- merged prep: pack | weight-repack | halo-zero | slots | init
__global__ __launch_bounds__(256) void prep_k(
    const float* __restrict__ cf, const float* __restrict__ we,
    const float* __restrict__ wd, const float* __restrict__ fv,
    unsigned short* __restrict__ Xp, unsigned short* __restrict__ WrE,
    unsigned short* __restrict__ WrD, int* __restrict__ smr,
    float* __restrict__ vd, float4* __restrict__ sraw4,
    float* __restrict__ lacc, unsigned* __restrict__ mm) {
  const int bx = blockIdx.x, t = threadIdx.x;
  if (bx < 2048) {                       // pack: cf NCHW f32 -> padded NHWC bf16
    int idx = bx * 256 + t;
    int ch = idx & 31, p = (idx >> 5) & 255, img = idx >> 13;
    int ic0 = ch * 8;
    const float* sp = cf + (size_t)img * 65536 + (size_t)ic0 * 256 + p;
    unsigned short h[8];
#pragma unroll
    for (int i = 0; i < 8; ++i) h[i] = f2bf(sp[i * 256]);
    int y = p >> 4, x = p & 15;
    uint4 u;
    u.x = h[0] | (h[1] << 16); u.y = h[2] | (h[3] << 16);
    u.z = h[4] | (h[5] << 16); u.w = h[6] | (h[7] << 16);
    *(uint4*)&Xp[(size_t)img * 82944 + (size_t)(y * 18 + x + 19) * 256 + ic0] = u;
  } else if (bx < 2624) {                // wrk: OIHW f32 -> Wr[oc][s][ic] bf16
    int idx = (bx - 2048) * 256 + t;
    int ch = idx & 31, rest = idx >> 5;
    int s = rest % 9, ocx = rest / 9;
    int oc = ocx & 255, cv = ocx >> 8;
    const float* w = cv ? wd : we;
    unsigned short* o = cv ? WrD : WrE;
    int ic0 = ch * 8;
    unsigned short h[8];
#pragma unroll
    for (int i = 0; i < 8; ++i) h[i] = f2bf(w[(size_t)oc * 2304 + (ic0 + i) * 9 + s]);
    uint4 u;
    u.x = h[0] | (h[1] << 16); u.y = h[2] | (h[3] << 16);
    u.z = h[4] | (h[5] << 16); u.w = h[6] | (h[7] << 16);
    *(uint4*)&o[(size_t)oc * 2304 + s * 256 + ic0] = u;
  } else if (bx < 2752) {                // halo zero: Xp imgs 0..63, Midp 64..127
    int img = bx - 2624;
    uint4* base = (uint4*)Xp + (size_t)img * 10368;
    uint4 z; z.x = z.y = z.z = z.w = 0;
    for (int it = t; it < 2176; it += 256) {
      int px = it >> 5, c = it & 31;
      int y, x;
      if (px < 18)      { y = 0;  x = px; }
      else if (px < 36) { y = 17; x = px - 18; }
      else if (px < 52) { y = px - 35; x = 0; }
      else              { y = px - 51; x = 17; }
      base[(y * 18 + x) * 32 + c] = z;
    }
  } else if (bx < 2784) {                // slots: rank budget + dest maps
    const int b = bx - 2752;
    const float v0 = fv[(size_t)b * 512 + t];
    const float v1 = fv[(size_t)b * 512 + 256 + t];
    const unsigned long long bal0 = __ballot(v0 > 0.1f);
    const unsigned long long bal1 = __ballot(v1 > 0.1f);
    __shared__ int cnt0[4], cnt1[4], fc[2];
    const int wid = t >> 6, lane = t & 63;
    if (lane == 0) { cnt0[wid] = __popcll(bal0); cnt1[wid] = __popcll(bal1); }
    smr[b * 256 + t] = -1;
    vd[b * 256 + t] = 0.f;
    __syncthreads();
    if (t == 0) {
      int c0 = cnt0[0] + cnt0[1] + cnt0[2] + cnt0[3];
      int c1 = cnt1[0] + cnt1[1] + cnt1[2] + cnt1[3];
      int total = c0 + c1;
      int f0, f1;
      if (total > 256) {
        int a0 = (int)rintf(256.0f * (float)c0 / (float)total);
        f0 = a0; f1 = 256 - a0;
      } else { f0 = c0; f1 = c1; }
      fc[0] = max(f0, 0); fc[1] = max(f1, 0);
    }
    __syncthreads();
    const int c0 = fc[0], c1 = fc[1];
    if (t < c0) { smr[b * 256 + t] = t; vd[b * 256 + t] = v0; }
    if (t < c1) {
      int d = c0 + t;
      if (d < 256) { smr[b * 256 + d] = 256 + t; vd[b * 256 + d] = v1; }
    }
  } else {                               // zero sraw (24 blocks) + init (1)
    int z = bx - 2784;
    if (z < 24) {
      float4 zz; zz.x = zz.y = zz.z = zz.w = 0.f;
      sraw4[z * 256 + t] = zz;
    } else if (t == 0) {
      lacc[0] = 0.f; mm[0] = 0xFFFFFFFFu; mm[1] = 0u;
    }
  }
}

// ---------------- MFMA conv: out[p][oc] = sum_k X[p][k]W[oc][k]
// Tile 64px x 128oc, BK=64, 36 kits, 3-deep pipeline (72KB LDS, 2 blk/CU).
// 1D grid = nimg*8; XCD-pinned: xcd = bid&7 owns imgs [xcd*ipx, xcd*ipx+ipx).
// EPI: 0=enc(relu->NHWC bf16), 1=dec+loss, 2=dec(rec)->NCHW f32 + minmax
template<int EPI, int IPSHIFT>
__global__ __launch_bounds__(256, 2) void convmma_k(
    const unsigned short* __restrict__ Xin, const unsigned short* __restrict__ Wr,
    const float* __restrict__ bias, const float* __restrict__ cfref,
    unsigned short* __restrict__ outp, float* __restrict__ outf,
    float* __restrict__ lacc, unsigned* __restrict__ mm) {
  __shared__ __align__(16) unsigned short S[3][12288];  // buf: A 8KB | B 16KB
  const int t = threadIdx.x, lane = t & 63, wave = t >> 6;
  const int L = blockIdx.x;
  const int xcd = L & 7, sl = L >> 3;
  const int img = xcd * (1 << IPSHIFT) + (sl & ((1 << IPSHIFT) - 1));
  const int tile = sl >> IPSHIFT;            // 0..7
  const int pt = tile >> 1, ot = tile & 1;

  int laneA[2], laneB[4];
  {
    const int rl = lane >> 3, q0 = lane & 7;
#pragma unroll
    for (int j = 0; j < 2; ++j) {
      int row = (wave * 2 + j) * 8 + rl;     // 0..63
      int p = pt * 64 + row, y = p >> 4, x = p & 15;
      laneA[j] = (y * 18 + x) * 512 + ((q0 ^ (row & 7)) * 16);
    }
#pragma unroll
    for (int j = 0; j < 4; ++j) {
      int row = (wave * 4 + j) * 8 + rl;     // 0..127
      laneB[j] = (ot * 128 + row) * 4608 + ((q0 ^ (row & 7)) * 16);
    }
  }
  const char* Ag = (const char*)Xin + (size_t)img * 165888;
  const char* Bg = (const char*)Wr;

  const int mlane = lane & 15, quad = lane >> 4;
  const int mw = wave >> 1, nw = wave & 1;
  int aoff[2][2], boff[4][2];
#pragma unroll
  for (int ks = 0; ks < 2; ++ks) {
#pragma unroll
    for (int i = 0; i < 2; ++i) {
      int rowm = mw * 32 + i * 16 + mlane;
      aoff[i][ks] = rowm * 128 + (((ks * 4 + quad) ^ (rowm & 7)) * 16);
    }
#pragma unroll
    for (int n = 0; n < 4; ++n) {
      int rown = nw * 64 + n * 16 + mlane;
      boff[n][ks] = 8192 + rown * 128 + (((ks * 4 + quad) ^ (rown & 7)) * 16);
    }
  }

  auto stage = [&](int kit, int buf) {       // 6 loads/thread
    int s = kit >> 2;
    int dy = s / 3, dx = s - dy * 3;
    int aG = (dy * 18 + dx) * 512 + (kit & 3) * 128;
    int bG = kit * 128;
    char* dst = (char*)S[buf];
#pragma unroll
    for (int j = 0; j < 2; ++j)
      gload_lds16(Ag + laneA[j] + aG, dst + (wave * 2 + j) * 1024);
#pragma unroll
    for (int j = 0; j < 4; ++j)
      gload_lds16(Bg + laneB[j] + bG, dst + 8192 + (wave * 4 + j) * 1024);
  };

  f32x4 acc[2][4] = {};
  auto compute = [&](int buf) {
    const char* Sb = (const char*)S[buf];
#pragma unroll
    for (int ks = 0; ks < 2; ++ks) {
      short8 af[2], bf[4];
#pragma unroll
      for (int i = 0; i < 2; ++i) af[i] = *(const short8*)(Sb + aoff[i][ks]);
#pragma unroll
      for (int n = 0; n < 4; ++n) bf[n] = *(const short8*)(Sb + boff[n][ks]);
#pragma unroll
      for (int i = 0; i < 2; ++i)
#pragma unroll
        for (int n = 0; n < 4; ++n)
          acc[i][n] = __builtin_amdgcn_mfma_f32_16x16x32_bf16(af[i], bf[n], acc[i][n], 0, 0, 0);
    }
  };

  stage(0, 0);
  stage(1, 1);
  int cur = 0, nxt = 2;
  for (int kit = 0; kit < 35; ++kit) {
    asm volatile("s_waitcnt vmcnt(6)" ::: "memory");  // oldest stage done; next stays in flight
    asm volatile("s_barrier" ::: "memory");
    if (kit + 2 < 36) stage(kit + 2, nxt);
    compute(cur);
    cur = (cur == 2) ? 0 : cur + 1;
    nxt = (nxt == 2) ? 0 : nxt + 1;
  }
  asm volatile("s_waitcnt vmcnt(0)" ::: "memory");    // tail kit: full drain
  asm volatile("s_barrier" ::: "memory");
  compute(cur);

  if (EPI == 0) {
#pragma unroll
    for (int i = 0; i < 2; ++i) {
      int m0 = pt * 64 + mw * 32 + i * 16 + quad * 4;
#pragma unroll
      for (int n = 0; n < 4; ++n) {
        int oc = ot * 128 + nw * 64 + n * 16 + mlane;
        float bv = bias[oc];
#pragma unroll
        for (int r = 0; r < 4; ++r) {
          int p = m0 + r;
          int y = p >> 4, x = p & 15;
          float v = fmaxf(acc[i][n][r] + bv, 0.f);
          outp[(size_t)img * 82944 + (size_t)(y * 18 + x + 19) * 256 + oc] = f2bf(v);
        }
      }
    }
  } else if (EPI == 1) {
    float ls = 0.f;
#pragma unroll
    for (int i = 0; i < 2; ++i) {
      int m0 = pt * 64 + mw * 32 + i * 16 + quad * 4;
#pragma unroll
      for (int n = 0; n < 4; ++n) {
        int oc = ot * 128 + nw * 64 + n * 16 + mlane;
        float bv = bias[oc];
        float4 c4 = *(const float4*)(cfref + (size_t)img * 65536 + (size_t)oc * 256 + m0);
        float d0 = acc[i][n][0] + bv - c4.x;
        float d1 = acc[i][n][1] + bv - c4.y;
        float d2 = acc[i][n][2] + bv - c4.z;
        float d3 = acc[i][n][3] + bv - c4.w;
        ls += d0 * d0 + d1 * d1 + d2 * d2 + d3 * d3;
      }
    }
#pragma unroll
    for (int off = 32; off; off >>= 1) ls += __shfl_down(ls, off);
    __shared__ float sred[4];
    if (lane == 0) sred[wave] = ls;
    __syncthreads();
    if (t == 0) atomicAdd(lacc, sred[0] + sred[1] + sred[2] + sred[3]);
  } else {
    float mn = INFINITY, mx = -INFINITY;
#pragma unroll
    for (int i = 0; i < 2; ++i) {
      int m0 = pt * 64 + mw * 32 + i * 16 + quad * 4;
#pragma unroll
      for (int n = 0; n < 4; ++n) {
        int oc = ot * 128 + nw * 64 + n * 16 + mlane;
        float bv = bias[oc];
        float4 v;
        v.x = acc[i][n][0] + bv; v.y = acc[i][n][1] + bv;
        v.z = acc[i][n][2] + bv; v.w = acc[i][n][3] + bv;
        mn = fminf(mn, fminf(fminf(v.x, v.y), fminf(v.z, v.w)));
        mx = fmaxf(mx, fmaxf(fmaxf(v.x, v.y), fmaxf(v.z, v.w)));
        *(float4*)(outf + (size_t)img * 65536 + (size_t)oc * 256 + m0) = v;
      }
    }
#pragma unroll
    for (int off = 32; off; off >>= 1) {
      mn = fminf(mn, __shfl_down(mn, off));
      mx = fmaxf(mx, __shfl_down(mx, off));
    }
    __shared__ float smn[4], smx[4];
    if (lane == 0) { smn[wave] = mn; smx[wave] = mx; }
    __syncthreads();
    if (t == 0) {
      mn = fminf(fminf(smn[0], smn[1]), fminf(smn[2], smn[3]));
      mx = fmaxf(fmaxf(smx[0], smx[1]), fmaxf(smx[2], smx[3]));
      atomicMin(&mm[0], mapf(mn));
      atomicMax(&mm[1], mapf(mx));
    }
  }
}

// ---------------- merged: ansb [0,1024) | bmt-transpose [1024,1152) | Recp halo [1152,1184)
__global__ __launch_bounds__(256) void ansbmt_k(
    const float* __restrict__ fs, const float* __restrict__ fd,
    const int* __restrict__ smr, const float* __restrict__ vd,
    unsigned short* __restrict__ Ans, unsigned short* __restrict__ BmT,
    unsigned short* __restrict__ Recp) {
  const int bx = blockIdx.x, t = threadIdx.x;
  if (bx < 1024) {                       // Ans[b][c][j] = ns[c][j]*v_j
    int idx = bx * 256 + t;
    int ch = idx & 31, c = (idx >> 5) & 255, b = idx >> 13;
    int j0 = ch * 8;
    int si = smr[b * 256 + c];
    unsigned short h[8] = {0, 0, 0, 0, 0, 0, 0, 0};
    if (si >= 0) {
      int m = si >> 8, r = si & 255;
      const float* fp = fs + (((size_t)b * 2 + m) * 256 + r) * 256 + j0;
      const float* vp = vd + b * 256 + j0;
#pragma unroll
      for (int i = 0; i < 8; ++i) h[i] = f2bf(fp[i] * vp[i]);
    }
    uint4 u;
    u.x = h[0] | (h[1] << 16); u.y = h[2] | (h[3] << 16);
    u.z = h[4] | (h[5] << 16); u.w = h[6] | (h[7] << 16);
    *(uint4*)&Ans[(size_t)b * 65536 + c * 256 + j0] = u;
  } else if (bx < 1152) {                // BmT[b][p][j] = fd[b,m_p,j,r_p]
    __shared__ float sIn[4096];          // 8 j x 2 m x 256 r
    const int b = (bx - 1024) >> 2, bz = (bx - 1024) & 3;
    const int sp = smr[b * 256 + t];
    const int m_p = sp >> 8, r_p = sp & 255;
    for (int jg = bz * 8; jg < bz * 8 + 8; ++jg) {
      __syncthreads();
#pragma unroll
      for (int u = 0; u < 4; ++u) {
        int q = t * 4 + u;
        int rr = q >> 6, w = q & 63;
        int m = rr >> 3, i = rr & 7;
        float4 f = ((const float4*)fd)[((size_t)(b * 2 + m) * 256 + jg * 8 + i) * 64 + w];
        *(float4*)&sIn[i * 512 + m * 256 + w * 4] = f;
      }
      __syncthreads();
      unsigned short h[8] = {0, 0, 0, 0, 0, 0, 0, 0};
      if (sp >= 0) {
#pragma unroll
        for (int i = 0; i < 8; ++i) h[i] = f2bf(sIn[i * 512 + m_p * 256 + r_p]);
      }
      uint4 u;
      u.x = h[0] | (h[1] << 16); u.y = h[2] | (h[3] << 16);
      u.z = h[4] | (h[5] << 16); u.w = h[6] | (h[7] << 16);
      *(uint4*)&BmT[(size_t)b * 65536 + t * 256 + jg * 8] = u;
    }
  } else {                               // Recp halo zero (32 imgs)
    int img = bx - 1152;
    uint4* base = (uint4*)Recp + (size_t)img * 10368;
    uint4 z; z.x = z.y = z.z = z.w = 0;
    for (int it = t; it < 2176; it += 256) {
      int px = it >> 5, c = it & 31;
      int y, x;
      if (px < 18)      { y = 0;  x = px; }
      else if (px < 36) { y = 17; x = px - 18; }
      else if (px < 52) { y = px - 35; x = 0; }
      else              { y = px - 51; x = 17; }
      base[(y * 18 + x) * 32 + c] = z;
    }
  }
}

// rec^T[p][c] = sum_j BmT[p][j]*Ans[c][j] -> Recp padded NHWC bf16
// Tile 64p x 64c, BK=64, 4 kits, dbuf. grid (16, 32): bx = pt*4 + ct.
__global__ __launch_bounds__(256, 4) void recgemm_k(const unsigned short* __restrict__ BmT,
                                                    const unsigned short* __restrict__ Ans,
                                                    unsigned short* __restrict__ Recp) {
  __shared__ __align__(16) unsigned short S[2][8192];
  const int t = threadIdx.x, lane = t & 63, wave = t >> 6;
  const int b = blockIdx.y, pt = blockIdx.x >> 2, ct = blockIdx.x & 3;

  int laneA[2], laneB[2];
#pragma unroll
  for (int j = 0; j < 2; ++j) {
    int id = (wave * 2 + j) * 64 + lane;
    int row = id >> 3, q = (id & 7) ^ (row & 7);
    laneA[j] = (pt * 64 + row) * 512 + q * 16;
    laneB[j] = (ct * 64 + row) * 512 + q * 16;
  }
  const char* Ag = (const char*)BmT + (size_t)b * 131072;
  const char* Bg = (const char*)Ans + (size_t)b * 131072;

  const int mlane = lane & 15, quad = lane >> 4;
  const int mw = wave >> 1, nw = wave & 1;
  int aoff[2][2], boff[2][2];
#pragma unroll
  for (int ks = 0; ks < 2; ++ks) {
#pragma unroll
    for (int i = 0; i < 2; ++i) {
      int rowm = mw * 32 + i * 16 + mlane;
      aoff[i][ks] = rowm * 128 + (((ks * 4 + quad) ^ (rowm & 7)) * 16);
      int rown = nw * 32 + i * 16 + mlane;
      boff[i][ks] = 8192 + rown * 128 + (((ks * 4 + quad) ^ (rown & 7)) * 16);
    }
  }

  auto stage = [&](int kit, int buf) {
    int g = kit * 128;
    char* dst = (char*)S[buf];
#pragma unroll
    for (int j = 0; j < 2; ++j)
      gload_lds16(Ag + laneA[j] + g, dst + (wave * 2 + j) * 1024);
#pragma unroll
    for (int j = 0; j < 2; ++j)
      gload_lds16(Bg + laneB[j] + g, dst + 8192 + (wave * 2 + j) * 1024);
  };

  f32x4 acc[2][2] = {};
  stage(0, 0);
  for (int kit = 0; kit < 4; ++kit) {
    int cur = kit & 1;
    asm volatile("s_waitcnt vmcnt(0)" ::: "memory");
    asm volatile("s_barrier" ::: "memory");
    if (kit + 1 < 4) stage(kit + 1, 1 - cur);
    const char* Sb = (const char*)S[cur];
#pragma unroll
    for (int ks = 0; ks < 2; ++ks) {
      short8 af[2], bf[2];
#pragma unroll
      for (int i = 0; i < 2; ++i) {
        af[i] = *(const short8*)(Sb + aoff[i][ks]);
        bf[i] = *(const short8*)(Sb + boff[i][ks]);
      }
#pragma unroll
      for (int i = 0; i < 2; ++i)
#pragma unroll
        for (int n = 0; n < 2; ++n)
          acc[i][n] = __builtin_amdgcn_mfma_f32_16x16x32_bf16(af[i], bf[n], acc[i][n], 0, 0, 0);
    }
  }

#pragma unroll
  for (int i = 0; i < 2; ++i) {
    int m0 = pt * 64 + mw * 32 + i * 16 + quad * 4;
#pragma unroll
    for (int n = 0; n < 2; ++n) {
      int cc = ct * 64 + nw * 32 + n * 16 + mlane;
#pragma unroll
      for (int r = 0; r < 4; ++r) {
        int p = m0 + r;
        int y = p >> 4, x = p & 15;
        Recp[(size_t)b * 82944 + (size_t)(y * 18 + x + 19) * 256 + cc] = f2bf(acc[i][n][r]);
      }
    }
  }
}

// 256->1 score conv partials, ic-split 8-way, atomicAdd into sraw (pre-zeroed)
__global__ __launch_bounds__(256) void score_conv_k(
    const float* __restrict__ rec2, const float* __restrict__ cf,
    const float* __restrict__ wval, const unsigned* __restrict__ mm,
    float* __restrict__ sraw) {
  const int b = blockIdx.x, phase = blockIdx.y, icc = blockIdx.z;
  const int t = threadIdx.x;
  const int row = t >> 4, col = t & 15;
  __shared__ float s_in[8 * 360];
  __shared__ float s_wv[72];
  for (int i = t; i < 8 * 360; i += 256) s_in[i] = 0.f;
  const float* src;
  float sc = 1.f, sh = 0.f;
  int wofs;
  if (phase == 0) {
    src = rec2 + (size_t)b * 65536;
    float mn = unmapf(mm[0]), mx = unmapf(mm[1]);
    sc = 2.f / (mx - mn);
    sh = -mn * sc - 1.f;
    wofs = 0;
  } else {
    src = cf + ((size_t)b * 2 + (phase - 1)) * 65536;
    wofs = 2304;
  }
  float acc = 0.f;
  for (int ic0 = icc * 32; ic0 < icc * 32 + 32; ic0 += 8) {
    __syncthreads();
#pragma unroll
    for (int i = 0; i < 8; ++i) {
      float v = src[(ic0 + i) * 256 + t];
      if (phase == 0) v = fmaf(v, sc, sh);
      s_in[i * 360 + (row + 1) * 20 + (col + 1)] = v;
    }
    if (t < 72) s_wv[t] = wval[wofs + ic0 * 9 + t];
    __syncthreads();
#pragma unroll
    for (int i = 0; i < 8; ++i)
#pragma unroll
      for (int ky = 0; ky < 3; ++ky)
#pragma unroll
        for (int kx = 0; kx < 3; ++kx)
          acc += s_in[i * 360 + (row + ky) * 20 + (col + kx)] * s_wv[i * 9 + ky * 3 + kx];
  }
  atomicAdd(&sraw[((size_t)b * 3 + phase) * 256 + t], acc);
}

__global__ void fuse_k(const float* __restrict__ cf, const float* __restrict__ rec2,
                       const float* __restrict__ sraw, const float* __restrict__ bval,
                       const unsigned* __restrict__ mm, const float* __restrict__ lacc,
                       float* __restrict__ outp) {
  const int idx = blockIdx.x * 256 + threadIdx.x;
  const int b = idx >> 16;
  const int rest = idx & 65535;
  const int pos = idx & 255;
  const float mn = unmapf(mm[0]), mx = unmapf(mm[1]);
  const float sc = 2.f / (mx - mn), sh = -mn * sc - 1.f;
  const float srec = sraw[(size_t)b * 768 + pos];
  const float sc0 = sraw[(size_t)b * 768 + 256 + pos];
  const float sc1 = sraw[(size_t)b * 768 + 512 + pos];
  const float bv = bval[0];
  const float z0 = fmaxf(srec + sc0 + bv, 0.f);
  const float z1 = fmaxf(srec + sc1 + bv, 0.f);
  const float s0 = 1.f / (1.f + expf(-z0));
  const float s1 = 1.f / (1.f + expf(-z1));
  const float w0 = 1.f / (1.f + expf(s1 - s0));  // softmax over 2 modalities
  const float w1 = 1.f - w0;
  const float rn = fmaf(rec2[idx], sc, sh);
  const float f0 = cf[(size_t)b * 131072 + rest];
  const float f1 = cf[(size_t)b * 131072 + 65536 + rest];
  outp[idx] = 0.2f * (w0 * f0 + w1 * f1) + 0.8f * rn;
  if (idx == 0) outp[2097152] = lacc[0] * (1.f / 4194304.f);
}

extern "C" void kernel_launch(void* const* d_in, const int* in_sizes, int n_in,
                              void* d_out, int out_size, void* d_ws, size_t ws_size,
                              hipStream_t stream) {
  const float* cf    = (const float*)d_in[0];
  const float* fs    = (const float*)d_in[1];
  const float* fv    = (const float*)d_in[2];
  const float* fd    = (const float*)d_in[3];
  const float* w_enc = (const float*)d_in[4];
  const float* b_enc = (const float*)d_in[5];
  const float* w_dec = (const float*)d_in[6];
  const float* b_dec = (const float*)d_in[7];
  const float* w_val = (const float*)d_in[8];
  const float* b_val = (const float*)d_in[9];
  float* out = (float*)d_out;
  float* wsf = (float*)d_ws;

  // ws layout (float offsets):
  //   Xp 64-img padded NHWC bf16 [0, 2654208) -- dead after enc conv
  //     Ans @0, BmT @1048576 (written after enc conv)
  //   Midp 64-img [2654208, 5308416) -- dead after loss conv
  //     Recp 32-img @2654208 (halo re-zeroed in ansbmt_k)
  unsigned short* Xp   = (unsigned short*)wsf;
  unsigned short* Ans  = (unsigned short*)wsf;
  unsigned short* BmT  = (unsigned short*)(wsf + 1048576);
  unsigned short* Midp = (unsigned short*)(wsf + 2654208);
  unsigned short* Recp = (unsigned short*)(wsf + 2654208);
  float* rec2 = wsf + 5308416;                    // 2,097,152 (NCHW f32)
  unsigned short* WrE = (unsigned short*)(wsf + 7405568);
  unsigned short* WrD = (unsigned short*)(wsf + 7700480);
  float* sraw = wsf + 7995392;                    // 24,576
  float* vd   = wsf + 8019968;                    // 8,192
  int*   smr  = (int*)(wsf + 8028160);            // 8,192
  float* lacc = wsf + 8036352;
  unsigned* mm = (unsigned*)(wsf + 8036354);

  prep_k<<<2809, 256, 0, stream>>>(cf, w_enc, w_dec, fv, Xp, WrE, WrD, smr, vd,
                                   (float4*)sraw, lacc, mm);
  convmma_k<0, 3><<<512, 256, 0, stream>>>(Xp, WrE, b_enc, nullptr, Midp, nullptr, nullptr, nullptr);
  convmma_k<1, 3><<<512, 256, 0, stream>>>(Midp, WrD, b_dec, cf, nullptr, nullptr, lacc, nullptr);
  ansbmt_k<<<1184, 256, 0, stream>>>(fs, fd, smr, vd, Ans, BmT, Recp);
  recgemm_k<<<dim3(16, 32), 256, 0, stream>>>(BmT, Ans, Recp);
  convmma_k<2, 2><<<256, 256, 0, stream>>>(Recp, WrD, b_dec, nullptr, nullptr, rec2, nullptr, mm);
  score_conv_k<<<dim3(32, 3, 8), 256, 0, stream>>>(rec2, cf, w_val, mm, sraw);
  fuse_k<<<8192, 256, 0, stream>>>(cf, rec2, sraw, b_val, mm, lacc, out);
}

// Round 7
// 215.767 us; speedup vs baseline: 1.2300x; 1.1257x over previous
//
#include <hip/hip_runtime.h>
#include <math.h>

// Shapes (fixed): B=32, M=2, C=256, H=W=16, N=256, DIM=256, THR=0.1, RATIO=0.8
// out: fused (32,256,16,16) = 2,097,152 floats, then auto_enc_loss (1 float)
//
// R7: convs as bf16 implicit GEMM with 128px x 128oc tiles, 512 threads
// (8 waves), BK=64, 2-deep 64KB LDS pipeline (stage k+1 after barrier; its
// loads fly across compute(k)), XCD-pinned. dec-loss conv + rec-dec conv
// merged into one 384-block dispatch (shared weights). 7 launches.

typedef __attribute__((ext_vector_type(8))) short short8;
typedef __attribute__((ext_vector_type(4))) float f32x4;

__device__ __forceinline__ void gload_lds16(const void* g, void* l) {
  __builtin_amdgcn_global_load_lds(
      (const __attribute__((address_space(1))) void*)g,
      (__attribute__((address_space(3))) void*)l, 16, 0, 0);
}

__device__ __forceinline__ unsigned short f2bf(float f) {
  unsigned u = __float_as_uint(f);
  unsigned r = (u + 0x7FFFu + ((u >> 16) & 1u)) >> 16;  // RNE
  return (unsigned short)r;
}

__device__ __forceinline__ unsigned mapf(float f) {
  unsigned u = __float_as_uint(f);
  return (u & 0x80000000u) ? ~u : (u | 0x80000000u);   // monotone float->uint
}
__device__ __forceinline__ float unmapf(unsigned u) {
  unsigned v = (u & 0x80000000u) ? (u & 0x7fffffffu) : ~u;
  return __uint_as_float(v);
}

// ---------------- merged prep: pack | weight-repack | halo-zero | slots | init
__global__ __launch_bounds__(256) void prep_k(
    const float* __restrict__ cf, const float* __restrict__ we,
    const float* __restrict__ wd, const float* __restrict__ fv,
    unsigned short* __restrict__ Xp, unsigned short* __restrict__ WrE,
    unsigned short* __restrict__ WrD, int* __restrict__ smr,
    float* __restrict__ vd, float4* __restrict__ sraw4,
    float* __restrict__ lacc, unsigned* __restrict__ mm) {
  const int bx = blockIdx.x, t = threadIdx.x;
  if (bx < 2048) {                       // pack: cf NCHW f32 -> padded NHWC bf16
    int idx = bx * 256 + t;
    int p = idx & 255, ch = (idx >> 8) & 31, img = idx >> 13;  // lanes ~ p: coalesced
    int ic0 = ch * 8;
    const float* sp = cf + (size_t)img * 65536 + (size_t)ic0 * 256 + p;
    unsigned short h[8];
#pragma unroll
    for (int i = 0; i < 8; ++i) h[i] = f2bf(sp[i * 256]);
    int y = p >> 4, x = p & 15;
    uint4 u;
    u.x = h[0] | (h[1] << 16); u.y = h[2] | (h[3] << 16);
    u.z = h[4] | (h[5] << 16); u.w = h[6] | (h[7] << 16);
    *(uint4*)&Xp[(size_t)img * 82944 + (size_t)(y * 18 + x + 19) * 256 + ic0] = u;
  } else if (bx < 2624) {                // wrk: OIHW f32 -> Wr[oc][s][ic] bf16
    int idx = (bx - 2048) * 256 + t;
    int ch = idx & 31, rest = idx >> 5;
    int s = rest % 9, ocx = rest / 9;
    int oc = ocx & 255, cv = ocx >> 8;
    const float* w = cv ? wd : we;
    unsigned short* o = cv ? WrD : WrE;
    int ic0 = ch * 8;
    unsigned short h[8];
#pragma unroll
    for (int i = 0; i < 8; ++i) h[i] = f2bf(w[(size_t)oc * 2304 + (ic0 + i) * 9 + s]);
    uint4 u;
    u.x = h[0] | (h[1] << 16); u.y = h[2] | (h[3] << 16);
    u.z = h[4] | (h[5] << 16); u.w = h[6] | (h[7] << 16);
    *(uint4*)&o[(size_t)oc * 2304 + s * 256 + ic0] = u;
  } else if (bx < 2752) {                // halo zero: Xp imgs 0..63, Midp 64..127
    int img = bx - 2624;
    uint4* base = (uint4*)Xp + (size_t)img * 10368;
    uint4 z; z.x = z.y = z.z = z.w = 0;
    for (int it = t; it < 2176; it += 256) {
      int px = it >> 5, c = it & 31;
      int y, x;
      if (px < 18)      { y = 0;  x = px; }
      else if (px < 36) { y = 17; x = px - 18; }
      else if (px < 52) { y = px - 35; x = 0; }
      else              { y = px - 51; x = 17; }
      base[(y * 18 + x) * 32 + c] = z;
    }
  } else if (bx < 2784) {                // slots: rank budget + dest maps
    const int b = bx - 2752;
    const float v0 = fv[(size_t)b * 512 + t];
    const float v1 = fv[(size_t)b * 512 + 256 + t];
    const unsigned long long bal0 = __ballot(v0 > 0.1f);
    const unsigned long long bal1 = __ballot(v1 > 0.1f);
    __shared__ int cnt0[4], cnt1[4], fc[2];
    const int wid = t >> 6, lane = t & 63;
    if (lane == 0) { cnt0[wid] = __popcll(bal0); cnt1[wid] = __popcll(bal1); }
    smr[b * 256 + t] = -1;
    vd[b * 256 + t] = 0.f;
    __syncthreads();
    if (t == 0) {
      int c0 = cnt0[0] + cnt0[1] + cnt0[2] + cnt0[3];
      int c1 = cnt1[0] + cnt1[1] + cnt1[2] + cnt1[3];
      int total = c0 + c1;
      int f0, f1;
      if (total > 256) {
        int a0 = (int)rintf(256.0f * (float)c0 / (float)total);
        f0 = a0; f1 = 256 - a0;
      } else { f0 = c0; f1 = c1; }
      fc[0] = max(f0, 0); fc[1] = max(f1, 0);
    }
    __syncthreads();
    const int c0 = fc[0], c1 = fc[1];
    if (t < c0) { smr[b * 256 + t] = t; vd[b * 256 + t] = v0; }
    if (t < c1) {
      int d = c0 + t;
      if (d < 256) { smr[b * 256 + d] = 256 + t; vd[b * 256 + d] = v1; }
    }
  } else {                               // zero sraw (24 blocks) + init (1)
    int z = bx - 2784;
    if (z < 24) {
      float4 zz; zz.x = zz.y = zz.z = zz.w = 0.f;
      sraw4[z * 256 + t] = zz;
    } else if (t == 0) {
      lacc[0] = 0.f; mm[0] = 0xFFFFFFFFu; mm[1] = 0u;
    }
  }
}

// ---------------- conv core pieces (128px x 128oc, BK=64, 512 threads) ----
// LDS buf (32KB): A [0,16KB) rows=pixel, B [16KB,32KB) rows=oc; row=128B of k.
// Chunk-XOR swizzle: LDS chunk sub holds global chunk sub^(row&7).

// enc: out[p][oc] = relu(sum_k X[p][k] W[oc][k] + b) -> padded NHWC bf16
__global__ __launch_bounds__(512, 4) void conv_enc_k(
    const unsigned short* __restrict__ Xin, const unsigned short* __restrict__ Wr,
    const float* __restrict__ bias, unsigned short* __restrict__ outp) {
  __shared__ __align__(16) char S[2][32768];
  const int t = threadIdx.x, lane = t & 63, wave = t >> 6;
  const int L = blockIdx.x;
  const int xcd = L & 7, sl = L >> 3;          // 256 blocks: sl 0..31
  const int img = xcd * 8 + (sl & 7);
  const int tile = sl >> 3;                    // 0..3
  const int pt = tile >> 1, ot = tile & 1;

  int laneA[2], laneB[2];
#pragma unroll
  for (int r = 0; r < 2; ++r) {
    int id = r * 512 + t;
    int row = id >> 3, sub = id & 7, q = sub ^ (row & 7);
    int p = pt * 128 + row, y = p >> 4, x = p & 15;
    laneA[r] = (y * 18 + x) * 512 + q * 16;
    laneB[r] = (ot * 128 + row) * 4608 + q * 16;
  }
  const char* Ag = (const char*)Xin + (size_t)img * 165888;
  const char* Bg = (const char*)Wr;

  const int mlane = lane & 15, quad = lane >> 4;
  const int mw = wave >> 1, nw = wave & 1;     // mw 0..3, nw 0..1
  int aoff[2][2], boff[4][2];
#pragma unroll
  for (int ks = 0; ks < 2; ++ks) {
#pragma unroll
    for (int i = 0; i < 2; ++i) {
      int rowm = mw * 32 + i * 16 + mlane;
      aoff[i][ks] = rowm * 128 + (((ks * 4 + quad) ^ (rowm & 7)) * 16);
    }
#pragma unroll
    for (int n = 0; n < 4; ++n) {
      int rown = nw * 64 + n * 16 + mlane;
      boff[n][ks] = 16384 + rown * 128 + (((ks * 4 + quad) ^ (rown & 7)) * 16);
    }
  }

  auto stage = [&](int kit, int buf) {         // 4 loads/thread
    int s = kit >> 2;
    int dy = s / 3, dx = s - dy * 3;
    int aG = (dy * 18 + dx) * 512 + (kit & 3) * 128;
    int bG = kit * 128;
    char* dst = S[buf];
#pragma unroll
    for (int r = 0; r < 2; ++r)
      gload_lds16(Ag + laneA[r] + aG, dst + r * 8192 + wave * 1024);
#pragma unroll
    for (int r = 0; r < 2; ++r)
      gload_lds16(Bg + laneB[r] + bG, dst + 16384 + r * 8192 + wave * 1024);
  };

  f32x4 acc[2][4] = {};
  auto compute = [&](int buf) {
    const char* Sb = S[buf];
#pragma unroll
    for (int ks = 0; ks < 2; ++ks) {
      short8 af[2], bf[4];
#pragma unroll
      for (int i = 0; i < 2; ++i) af[i] = *(const short8*)(Sb + aoff[i][ks]);
#pragma unroll
      for (int n = 0; n < 4; ++n) bf[n] = *(const short8*)(Sb + boff[n][ks]);
#pragma unroll
      for (int i = 0; i < 2; ++i)
#pragma unroll
        for (int n = 0; n < 4; ++n)
          acc[i][n] = __builtin_amdgcn_mfma_f32_16x16x32_bf16(af[i], bf[n], acc[i][n], 0, 0, 0);
    }
  };

  stage(0, 0);
  for (int kit = 0; kit < 36; ++kit) {
    int cur = kit & 1;
    asm volatile("s_waitcnt vmcnt(0)" ::: "memory");
    asm volatile("s_barrier" ::: "memory");
    if (kit + 1 < 36) stage(kit + 1, 1 - cur);  // flies across compute(cur)
    compute(cur);
  }

#pragma unroll
  for (int i = 0; i < 2; ++i) {
    int m0 = pt * 128 + mw * 32 + i * 16 + quad * 4;
#pragma unroll
    for (int n = 0; n < 4; ++n) {
      int oc = ot * 128 + nw * 64 + n * 16 + mlane;
      float bv = bias[oc];
#pragma unroll
      for (int r = 0; r < 4; ++r) {
        int p = m0 + r;
        int y = p >> 4, x = p & 15;
        float v = fmaxf(acc[i][n][r] + bv, 0.f);
        outp[(size_t)img * 82944 + (size_t)(y * 18 + x + 19) * 256 + oc] = f2bf(v);
      }
    }
  }
}

// dec merged: units 0..63 = dec(Midp)+loss vs cf; units 64..95 = dec(Recp)->rec2+minmax
__global__ __launch_bounds__(512, 4) void conv_dec_k(
    const unsigned short* __restrict__ Midp, const unsigned short* __restrict__ Recp,
    const unsigned short* __restrict__ Wr, const float* __restrict__ bias,
    const float* __restrict__ cfref, float* __restrict__ rec2,
    float* __restrict__ lacc, unsigned* __restrict__ mm) {
  __shared__ __align__(16) char S[2][32768];
  const int t = threadIdx.x, lane = t & 63, wave = t >> 6;
  const int L = blockIdx.x;
  const int xcd = L & 7, sl = L >> 3;          // 384 blocks: sl 0..47
  const int u12 = sl % 12, tile = sl / 12;     // tile 0..3
  const int unit = xcd * 12 + u12;             // 0..95
  const bool isLoss = unit < 64;
  const int pt = tile >> 1, ot = tile & 1;

  int laneA[2], laneB[2];
#pragma unroll
  for (int r = 0; r < 2; ++r) {
    int id = r * 512 + t;
    int row = id >> 3, sub = id & 7, q = sub ^ (row & 7);
    int p = pt * 128 + row, y = p >> 4, x = p & 15;
    laneA[r] = (y * 18 + x) * 512 + q * 16;
    laneB[r] = (ot * 128 + row) * 4608 + q * 16;
  }
  const char* Ag = isLoss ? (const char*)Midp + (size_t)unit * 165888
                          : (const char*)Recp + (size_t)(unit - 64) * 165888;
  const char* Bg = (const char*)Wr;

  const int mlane = lane & 15, quad = lane >> 4;
  const int mw = wave >> 1, nw = wave & 1;
  int aoff[2][2], boff[4][2];
#pragma unroll
  for (int ks = 0; ks < 2; ++ks) {
#pragma unroll
    for (int i = 0; i < 2; ++i) {
      int rowm = mw * 32 + i * 16 + mlane;
      aoff[i][ks] = rowm * 128 + (((ks * 4 + quad) ^ (rowm & 7)) * 16);
    }
#pragma unroll
    for (int n = 0; n < 4; ++n) {
      int rown = nw * 64 + n * 16 + mlane;
      boff[n][ks] = 16384 + rown * 128 + (((ks * 4 + quad) ^ (rown & 7)) * 16);
    }
  }

  auto stage = [&](int kit, int buf) {
    int s = kit >> 2;
    int dy = s / 3, dx = s - dy * 3;
    int aG = (dy * 18 + dx) * 512 + (kit & 3) * 128;
    int bG = kit * 128;
    char* dst = S[buf];
#pragma unroll
    for (int r = 0; r < 2; ++r)
      gload_lds16(Ag + laneA[r] + aG, dst + r * 8192 + wave * 1024);
#pragma unroll
    for (int r = 0; r < 2; ++r)
      gload_lds16(Bg + laneB[r] + bG, dst + 16384 + r * 8192 + wave * 1024);
  };

  f32x4 acc[2][4] = {};
  auto compute = [&](int buf) {
    const char* Sb = S[buf];
#pragma unroll
    for (int ks = 0; ks < 2; ++ks) {
      short8 af[2], bf[4];
#pragma unroll
      for (int i = 0; i < 2; ++i) af[i] = *(const short8*)(Sb + aoff[i][ks]);
#pragma unroll
      for (int n = 0; n < 4; ++n) bf[n] = *(const short8*)(Sb + boff[n][ks]);
#pragma unroll
      for (int i = 0; i < 2; ++i)
#pragma unroll
        for (int n = 0; n < 4; ++n)
          acc[i][n] = __builtin_amdgcn_mfma_f32_16x16x32_bf16(af[i], bf[n], acc[i][n], 0, 0, 0);
    }
  };

  stage(0, 0);
  for (int kit = 0; kit < 36; ++kit) {
    int cur = kit & 1;
    asm volatile("s_waitcnt vmcnt(0)" ::: "memory");
    asm volatile("s_barrier" ::: "memory");
    if (kit + 1 < 36) stage(kit + 1, 1 - cur);
    compute(cur);
  }

  if (isLoss) {
    float ls = 0.f;
#pragma unroll
    for (int i = 0; i < 2; ++i) {
      int m0 = pt * 128 + mw * 32 + i * 16 + quad * 4;
#pragma unroll
      for (int n = 0; n < 4; ++n) {
        int oc = ot * 128 + nw * 64 + n * 16 + mlane;
        float bv = bias[oc];
        float4 c4 = *(const float4*)(cfref + (size_t)unit * 65536 + (size_t)oc * 256 + m0);
        float d0 = acc[i][n][0] + bv - c4.x;
        float d1 = acc[i][n][1] + bv - c4.y;
        float d2 = acc[i][n][2] + bv - c4.z;
        float d3 = acc[i][n][3] + bv - c4.w;
        ls += d0 * d0 + d1 * d1 + d2 * d2 + d3 * d3;
      }
    }
#pragma unroll
    for (int off = 32; off; off >>= 1) ls += __shfl_down(ls, off);
    __shared__ float sred[8];
    if (lane == 0) sred[wave] = ls;
    __syncthreads();
    if (t == 0) {
      float s = 0.f;
#pragma unroll
      for (int w = 0; w < 8; ++w) s += sred[w];
      atomicAdd(lacc, s);
    }
  } else {
    const int img2 = unit - 64;
    float mn = INFINITY, mx = -INFINITY;
#pragma unroll
    for (int i = 0; i < 2; ++i) {
      int m0 = pt * 128 + mw * 32 + i * 16 + quad * 4;
#pragma unroll
      for (int n = 0; n < 4; ++n) {
        int oc = ot * 128 + nw * 64 + n * 16 + mlane;
        float bv = bias[oc];
        float4 v;
        v.x = acc[i][n][0] + bv; v.y = acc[i][n][1] + bv;
        v.z = acc[i][n][2] + bv; v.w = acc[i][n][3] + bv;
        mn = fminf(mn, fminf(fminf(v.x, v.y), fminf(v.z, v.w)));
        mx = fmaxf(mx, fmaxf(fmaxf(v.x, v.y), fmaxf(v.z, v.w)));
        *(float4*)(rec2 + (size_t)img2 * 65536 + (size_t)oc * 256 + m0) = v;
      }
    }
#pragma unroll
    for (int off = 32; off; off >>= 1) {
      mn = fminf(mn, __shfl_down(mn, off));
      mx = fmaxf(mx, __shfl_down(mx, off));
    }
    __shared__ float smn[8], smx[8];
    if (lane == 0) { smn[wave] = mn; smx[wave] = mx; }
    __syncthreads();
    if (t == 0) {
      float a = INFINITY, b2 = -INFINITY;
#pragma unroll
      for (int w = 0; w < 8; ++w) { a = fminf(a, smn[w]); b2 = fmaxf(b2, smx[w]); }
      atomicMin(&mm[0], mapf(a));
      atomicMax(&mm[1], mapf(b2));
    }
  }
}

// ---------------- merged: ansb [0,1024) | bmt-transpose [1024,1152) | Recp halo [1152,1184)
__global__ __launch_bounds__(256) void ansbmt_k(
    const float* __restrict__ fs, const float* __restrict__ fd,
    const int* __restrict__ smr, const float* __restrict__ vd,
    unsigned short* __restrict__ Ans, unsigned short* __restrict__ BmT,
    unsigned short* __restrict__ Recp) {
  const int bx = blockIdx.x, t = threadIdx.x;
  if (bx < 1024) {                       // Ans[b][c][j] = ns[c][j]*v_j
    int idx = bx * 256 + t;
    int ch = idx & 31, c = (idx >> 5) & 255, b = idx >> 13;
    int j0 = ch * 8;
    int si = smr[b * 256 + c];
    unsigned short h[8] = {0, 0, 0, 0, 0, 0, 0, 0};
    if (si >= 0) {
      int m = si >> 8, r = si & 255;
      const float* fp = fs + (((size_t)b * 2 + m) * 256 + r) * 256 + j0;
      const float* vp = vd + b * 256 + j0;
#pragma unroll
      for (int i = 0; i < 8; ++i) h[i] = f2bf(fp[i] * vp[i]);
    }
    uint4 u;
    u.x = h[0] | (h[1] << 16); u.y = h[2] | (h[3] << 16);
    u.z = h[4] | (h[5] << 16); u.w = h[6] | (h[7] << 16);
    *(uint4*)&Ans[(size_t)b * 65536 + c * 256 + j0] = u;
  } else if (bx < 1152) {                // BmT[b][p][j] = fd[b,m_p,j,r_p]
    __shared__ float sIn[4096];          // 8 j x 2 m x 256 r
    const int b = (bx - 1024) >> 2, bz = (bx - 1024) & 3;
    const int sp = smr[b * 256 + t];
    const int m_p = sp >> 8, r_p = sp & 255;
    for (int jg = bz * 8; jg < bz * 8 + 8; ++jg) {
      __syncthreads();
#pragma unroll
      for (int u = 0; u < 4; ++u) {
        int q = t * 4 + u;
        int rr = q >> 6, w = q & 63;
        int m = rr >> 3, i = rr & 7;
        float4 f = ((const float4*)fd)[((size_t)(b * 2 + m) * 256 + jg * 8 + i) * 64 + w];
        *(float4*)&sIn[i * 512 + m * 256 + w * 4] = f;
      }
      __syncthreads();
      unsigned short h[8] = {0, 0, 0, 0, 0, 0, 0, 0};
      if (sp >= 0) {
#pragma unroll
        for (int i = 0; i < 8; ++i) h[i] = f2bf(sIn[i * 512 + m_p * 256 + r_p]);
      }
      uint4 u;
      u.x = h[0] | (h[1] << 16); u.y = h[2] | (h[3] << 16);
      u.z = h[4] | (h[5] << 16); u.w = h[6] | (h[7] << 16);
      *(uint4*)&BmT[(size_t)b * 65536 + t * 256 + jg * 8] = u;
    }
  } else {                               // Recp halo zero (32 imgs)
    int img = bx - 1152;
    uint4* base = (uint4*)Recp + (size_t)img * 10368;
    uint4 z; z.x = z.y = z.z = z.w = 0;
    for (int it = t; it < 2176; it += 256) {
      int px = it >> 5, c = it & 31;
      int y, x;
      if (px < 18)      { y = 0;  x = px; }
      else if (px < 36) { y = 17; x = px - 18; }
      else if (px < 52) { y = px - 35; x = 0; }
      else              { y = px - 51; x = 17; }
      base[(y * 18 + x) * 32 + c] = z;
    }
  }
}

// rec^T[p][c] = sum_j BmT[p][j]*Ans[c][j] -> Recp padded NHWC bf16
__global__ __launch_bounds__(256, 4) void recgemm_k(const unsigned short* __restrict__ BmT,
                                                    const unsigned short* __restrict__ Ans,
                                                    unsigned short* __restrict__ Recp) {
  __shared__ __align__(16) unsigned short S[2][8192];
  const int t = threadIdx.x, lane = t & 63, wave = t >> 6;
  const int b = blockIdx.y, pt = blockIdx.x >> 2, ct = blockIdx.x & 3;

  int laneA[2], laneB[2];
#pragma unroll
  for (int j = 0; j < 2; ++j) {
    int id = (wave * 2 + j) * 64 + lane;
    int row = id >> 3, q = (id & 7) ^ (row & 7);
    laneA[j] = (pt * 64 + row) * 512 + q * 16;
    laneB[j] = (ct * 64 + row) * 512 + q * 16;
  }
  const char* Ag = (const char*)BmT + (size_t)b * 131072;
  const char* Bg = (const char*)Ans + (size_t)b * 131072;

  const int mlane = lane & 15, quad = lane >> 4;
  const int mw = wave >> 1, nw = wave & 1;
  int aoff[2][2], boff[2][2];
#pragma unroll
  for (int ks = 0; ks < 2; ++ks) {
#pragma unroll
    for (int i = 0; i < 2; ++i) {
      int rowm = mw * 32 + i * 16 + mlane;
      aoff[i][ks] = rowm * 128 + (((ks * 4 + quad) ^ (rowm & 7)) * 16);
      int rown = nw * 32 + i * 16 + mlane;
      boff[i][ks] = 8192 + rown * 128 + (((ks * 4 + quad) ^ (rown & 7)) * 16);
    }
  }

  auto stage = [&](int kit, int buf) {
    int g = kit * 128;
    char* dst = (char*)S[buf];
#pragma unroll
    for (int j = 0; j < 2; ++j)
      gload_lds16(Ag + laneA[j] + g, dst + (wave * 2 + j) * 1024);
#pragma unroll
    for (int j = 0; j < 2; ++j)
      gload_lds16(Bg + laneB[j] + g, dst + 8192 + (wave * 2 + j) * 1024);
  };

  f32x4 acc[2][2] = {};
  stage(0, 0);
  for (int kit = 0; kit < 4; ++kit) {
    int cur = kit & 1;
    asm volatile("s_waitcnt vmcnt(0)" ::: "memory");
    asm volatile("s_barrier" ::: "memory");
    if (kit + 1 < 4) stage(kit + 1, 1 - cur);
    const char* Sb = (const char*)S[cur];
#pragma unroll
    for (int ks = 0; ks < 2; ++ks) {
      short8 af[2], bf[2];
#pragma unroll
      for (int i = 0; i < 2; ++i) {
        af[i] = *(const short8*)(Sb + aoff[i][ks]);
        bf[i] = *(const short8*)(Sb + boff[i][ks]);
      }
#pragma unroll
      for (int i = 0; i < 2; ++i)
#pragma unroll
        for (int n = 0; n < 2; ++n)
          acc[i][n] = __builtin_amdgcn_mfma_f32_16x16x32_bf16(af[i], bf[n], acc[i][n], 0, 0, 0);
    }
  }

#pragma unroll
  for (int i = 0; i < 2; ++i) {
    int m0 = pt * 64 + mw * 32 + i * 16 + quad * 4;
#pragma unroll
    for (int n = 0; n < 2; ++n) {
      int cc = ct * 64 + nw * 32 + n * 16 + mlane;
#pragma unroll
      for (int r = 0; r < 4; ++r) {
        int p = m0 + r;
        int y = p >> 4, x = p & 15;
        Recp[(size_t)b * 82944 + (size_t)(y * 18 + x + 19) * 256 + cc] = f2bf(acc[i][n][r]);
      }
    }
  }
}

// 256->1 score conv partials, ic-split 8-way, atomicAdd into sraw (pre-zeroed)
__global__ __launch_bounds__(256) void score_conv_k(
    const float* __restrict__ rec2, const float* __restrict__ cf,
    const float* __restrict__ wval, const unsigned* __restrict__ mm,
    float* __restrict__ sraw) {
  const int b = blockIdx.x, phase = blockIdx.y, icc = blockIdx.z;
  const int t = threadIdx.x;
  const int row = t >> 4, col = t & 15;
  __shared__ float s_in[8 * 360];
  __shared__ float s_wv[72];
  for (int i = t; i < 8 * 360; i += 256) s_in[i] = 0.f;
  const float* src;
  float sc = 1.f, sh = 0.f;
  int wofs;
  if (phase == 0) {
    src = rec2 + (size_t)b * 65536;
    float mn = unmapf(mm[0]), mx = unmapf(mm[1]);
    sc = 2.f / (mx - mn);
    sh = -mn * sc - 1.f;
    wofs = 0;
  } else {
    src = cf + ((size_t)b * 2 + (phase - 1)) * 65536;
    wofs = 2304;
  }
  float acc = 0.f;
  for (int ic0 = icc * 32; ic0 < icc * 32 + 32; ic0 += 8) {
    __syncthreads();
#pragma unroll
    for (int i = 0; i < 8; ++i) {
      float v = src[(ic0 + i) * 256 + t];
      if (phase == 0) v = fmaf(v, sc, sh);
      s_in[i * 360 + (row + 1) * 20 + (col + 1)] = v;
    }
    if (t < 72) s_wv[t] = wval[wofs + ic0 * 9 + t];
    __syncthreads();
#pragma unroll
    for (int i = 0; i < 8; ++i)
#pragma unroll
      for (int ky = 0; ky < 3; ++ky)
#pragma unroll
        for (int kx = 0; kx < 3; ++kx)
          acc += s_in[i * 360 + (row + ky) * 20 + (col + kx)] * s_wv[i * 9 + ky * 3 + kx];
  }
  atomicAdd(&sraw[((size_t)b * 3 + phase) * 256 + t], acc);
}

__global__ void fuse_k(const float* __restrict__ cf, const float* __restrict__ rec2,
                       const float* __restrict__ sraw, const float* __restrict__ bval,
                       const unsigned* __restrict__ mm, const float* __restrict__ lacc,
                       float* __restrict__ outp) {
  const int idx = blockIdx.x * 256 + threadIdx.x;
  const int b = idx >> 16;
  const int rest = idx & 65535;
  const int pos = idx & 255;
  const float mn = unmapf(mm[0]), mx = unmapf(mm[1]);
  const float sc = 2.f / (mx - mn), sh = -mn * sc - 1.f;
  const float srec = sraw[(size_t)b * 768 + pos];
  const float sc0 = sraw[(size_t)b * 768 + 256 + pos];
  const float sc1 = sraw[(size_t)b * 768 + 512 + pos];
  const float bv = bval[0];
  const float z0 = fmaxf(srec + sc0 + bv, 0.f);
  const float z1 = fmaxf(srec + sc1 + bv, 0.f);
  const float s0 = 1.f / (1.f + expf(-z0));
  const float s1 = 1.f / (1.f + expf(-z1));
  const float w0 = 1.f / (1.f + expf(s1 - s0));  // softmax over 2 modalities
  const float w1 = 1.f - w0;
  const float rn = fmaf(rec2[idx], sc, sh);
  const float f0 = cf[(size_t)b * 131072 + rest];
  const float f1 = cf[(size_t)b * 131072 + 65536 + rest];
  outp[idx] = 0.2f * (w0 * f0 + w1 * f1) + 0.8f * rn;
  if (idx == 0) outp[2097152] = lacc[0] * (1.f / 4194304.f);
}

extern "C" void kernel_launch(void* const* d_in, const int* in_sizes, int n_in,
                              void* d_out, int out_size, void* d_ws, size_t ws_size,
                              hipStream_t stream) {
  const float* cf    = (const float*)d_in[0];
  const float* fs    = (const float*)d_in[1];
  const float* fv    = (const float*)d_in[2];
  const float* fd    = (const float*)d_in[3];
  const float* w_enc = (const float*)d_in[4];
  const float* b_enc = (const float*)d_in[5];
  const float* w_dec = (const float*)d_in[6];
  const float* b_dec = (const float*)d_in[7];
  const float* w_val = (const float*)d_in[8];
  const float* b_val = (const float*)d_in[9];
  float* out = (float*)d_out;
  float* wsf = (float*)d_ws;

  // ws layout (float offsets) — NO aliasing this round (~46 MB of ws):
  unsigned short* Xp   = (unsigned short*)wsf;                  // 64 img padded NHWC
  unsigned short* Midp = (unsigned short*)(wsf + 2654208);      // 64 img (halo: prep imgs 64..127)
  unsigned short* Recp = (unsigned short*)(wsf + 5308416);      // 32 img
  float* rec2 = wsf + 6635520;                                  // 2,097,152 NCHW f32
  unsigned short* WrE = (unsigned short*)(wsf + 8732672);
  unsigned short* WrD = (unsigned short*)(wsf + 9027584);
  unsigned short* Ans = (unsigned short*)(wsf + 9322496);
  unsigned short* BmT = (unsigned short*)(wsf + 10371072);
  float* sraw = wsf + 11419648;                                 // 24,576
  float* vd   = wsf + 11444224;                                 // 8,192
  int*   smr  = (int*)(wsf + 11452416);                         // 8,192
  float* lacc = wsf + 11460608;
  unsigned* mm = (unsigned*)(wsf + 11460609);

  prep_k<<<2809, 256, 0, stream>>>(cf, w_enc, w_dec, fv, Xp, WrE, WrD, smr, vd,
                                   (float4*)sraw, lacc, mm);
  ansbmt_k<<<1184, 256, 0, stream>>>(fs, fd, smr, vd, Ans, BmT, Recp);
  recgemm_k<<<dim3(16, 32), 256, 0, stream>>>(BmT, Ans, Recp);
  conv_enc_k<<<256, 512, 0, stream>>>(Xp, WrE, b_enc, Midp);
  conv_dec_k<<<384, 512, 0, stream>>>(Midp, Recp, WrD, b_dec, cf, rec2, lacc, mm);
  score_conv_k<<<dim3(32, 3, 8), 256, 0, stream>>>(rec2, cf, w_val, mm, sraw);
  fuse_k<<<8192, 256, 0, stream>>>(cf, rec2, sraw, b_val, mm, lacc, out);
}